// Round 1
// baseline (544.886 us; speedup 1.0000x reference)
//
#include <hip/hip_runtime.h>
#include <cmath>

#define TSX 32
#define TSY 32
#define HALO 5
#define NCOLS 42      // TSX + 2*HALO
#define CHROWS 26     // 16 + 2*HALO  (half-tile row chunk)
#define RSTR 44       // raw row stride (floats)
#define VSTR 44       // vb  row stride (floats), multiple of 4 for b128
#define WIDTH 512
#define HEIGHT 512

struct GW { float g[11]; };

__device__ __forceinline__ float ssim_term(float mu1, float mu2,
                                           float x2b, float y2b, float xyb)
{
    const float C1 = 1e-4f, C2 = 9e-4f;
    float mu12 = mu1 * mu2;
    float num  = (2.f * mu12 + C1) * (2.f * (xyb - mu12) + C2);
    float den  = (mu1 * mu1 + mu2 * mu2 + C1) *
                 ((x2b - mu1 * mu1) + (y2b - mu2 * mu2) + C2);
    return num / den;
}

__global__ __launch_bounds__(256)
void ssim_tile(const float* __restrict__ fI, const float* __restrict__ aI,
               const float* __restrict__ bI, float* __restrict__ gsum,
               GW gw, int W, int H)
{
    __shared__ __align__(16) float raw[3][CHROWS * RSTR];
    __shared__ __align__(16) float vb[8][TSY * VSTR];
    __shared__ float red[4];

    const int tid = threadIdx.x;
    const int x0 = blockIdx.x * TSX;
    const int y0 = blockIdx.y * TSY;
    const size_t pbase = (size_t)blockIdx.z * (size_t)(W * H);

    // Two 16-output-row chunks: stage 26 input rows, vertical-blur into vb.
    for (int c = 0; c < 2; ++c) {
        if (c) __syncthreads();              // protect raw from overwrite
        const int yb = y0 + 16 * c - HALO;
        // ---- phase 1: global -> LDS raw tile (zero-padded borders) ----
        for (int a = 0; a < 3; ++a) {
            const float* sp = (a == 0) ? fI : (a == 1) ? aI : bI;
            for (int idx = tid; idx < CHROWS * NCOLS; idx += 256) {
                int r = idx / NCOLS;
                int j = idx - r * NCOLS;
                int yy = yb + r;
                int xx = x0 - HALO + j;
                float v = 0.f;
                if ((unsigned)yy < (unsigned)H && (unsigned)xx < (unsigned)W)
                    v = sp[pbase + (size_t)yy * W + xx];
                raw[a][r * RSTR + j] = v;
            }
        }
        __syncthreads();
        // ---- phase 2: vertical blur of 8 fields (products on the fly) ----
        // task = (col j, 2-row group rg): 42*8 = 336 tasks
        for (int idx = tid; idx < NCOLS * 8; idx += 256) {
            int j  = idx % NCOLS;
            int rg = idx / NCOLS;            // 0..7 -> local out rows 2rg,2rg+1
            float acc0[8], acc1[8];
            #pragma unroll
            for (int q = 0; q < 8; ++q) { acc0[q] = 0.f; acc1[q] = 0.f; }
            #pragma unroll
            for (int k = 0; k < 12; ++k) {
                int i = 2 * rg + k;
                float a0 = raw[0][i * RSTR + j];
                float a1 = raw[1][i * RSTR + j];
                float a2 = raw[2][i * RSTR + j];
                float p[8];
                p[0] = a0; p[1] = a1; p[2] = a2;
                p[3] = a0 * a0; p[4] = a1 * a1; p[5] = a2 * a2;
                p[6] = a0 * a1; p[7] = a0 * a2;
                if (k <= 10) {
                    float w = gw.g[k];
                    #pragma unroll
                    for (int q = 0; q < 8; ++q) acc0[q] = fmaf(w, p[q], acc0[q]);
                }
                if (k >= 1) {
                    float w = gw.g[k - 1];
                    #pragma unroll
                    for (int q = 0; q < 8; ++q) acc1[q] = fmaf(w, p[q], acc1[q]);
                }
            }
            int R = 16 * c + 2 * rg;
            #pragma unroll
            for (int q = 0; q < 8; ++q) {
                vb[q][R * VSTR + j]       = acc0[q];
                vb[q][(R + 1) * VSTR + j] = acc1[q];
            }
        }
    }
    __syncthreads();

    // ---- phase 3: horizontal blur (vector LDS reads) + SSIM ----
    // thread -> (row r, 4-col strip s); 32 rows * 8 strips = 256 threads
    const int r = tid >> 3;
    const int s = tid & 7;
    float res[8][4];
    #pragma unroll
    for (int q = 0; q < 8; ++q) {
        const float4* vp = (const float4*)(&vb[q][r * VSTR + 4 * s]);
        float4 w0 = vp[0], w1 = vp[1], w2 = vp[2], w3 = vp[3];
        float vr[16] = { w0.x, w0.y, w0.z, w0.w,  w1.x, w1.y, w1.z, w1.w,
                         w2.x, w2.y, w2.z, w2.w,  w3.x, w3.y, w3.z, w3.w };
        #pragma unroll
        for (int jj = 0; jj < 4; ++jj) {
            float acc = 0.f;
            #pragma unroll
            for (int t = 0; t < 11; ++t) acc = fmaf(gw.g[t], vr[jj + t], acc);
            res[q][jj] = acc;
        }
    }
    float part = 0.f;
    #pragma unroll
    for (int jj = 0; jj < 4; ++jj) {
        // fields: 0=F 1=A 2=B 3=F2 4=A2 5=B2 6=FA 7=FB
        part += ssim_term(res[0][jj], res[1][jj], res[3][jj], res[4][jj], res[6][jj]);
        part += ssim_term(res[0][jj], res[2][jj], res[3][jj], res[5][jj], res[7][jj]);
    }

    // ---- phase 4: block reduction -> one atomic ----
    #pragma unroll
    for (int off = 32; off > 0; off >>= 1) part += __shfl_down(part, off);
    if ((tid & 63) == 0) red[tid >> 6] = part;
    __syncthreads();
    if (tid == 0) atomicAdd(gsum, red[0] + red[1] + red[2] + red[3]);
}

__global__ void ssim_final(const float* __restrict__ gsum,
                           float* __restrict__ out, float invTwoN)
{
    out[0] = 1.f - gsum[0] * invTwoN;
}

extern "C" void kernel_launch(void* const* d_in, const int* in_sizes, int n_in,
                              void* d_out, int out_size, void* d_ws, size_t ws_size,
                              hipStream_t stream)
{
    const float* f  = (const float*)d_in[0];
    const float* s1 = (const float*)d_in[1];
    const float* s2 = (const float*)d_in[2];
    float* out  = (float*)d_out;
    float* gsum = (float*)d_ws;

    const int W = WIDTH, H = HEIGHT;
    const int N = in_sizes[0];          // 48 * 512 * 512
    const int planes = N / (W * H);

    // Gaussian window (computed in double on host, matches numpy)
    GW gw;
    double gd[11], gs = 0.0;
    for (int i = 0; i < 11; ++i) {
        double d = (double)(i - 5);
        gd[i] = exp(-(d * d) / 4.5);    // 2*sigma^2 = 4.5
        gs += gd[i];
    }
    for (int i = 0; i < 11; ++i) gw.g[i] = (float)(gd[i] / gs);

    hipMemsetAsync(d_ws, 0, sizeof(float), stream);
    dim3 grid(W / TSX, H / TSY, planes);
    ssim_tile<<<grid, dim3(256), 0, stream>>>(f, s1, s2, gsum, gw, W, H);
    ssim_final<<<1, 1, 0, stream>>>(gsum, out, 0.5f / (float)N);
}